// Round 4
// baseline (2499.805 us; speedup 1.0000x reference)
//
#include <hip/hip_runtime.h>

typedef short s16x8 __attribute__((ext_vector_type(8)));
typedef float f32x4 __attribute__((ext_vector_type(4)));

__device__ inline float b2f(short s) {
  union { unsigned int u; float f; } v;
  v.u = ((unsigned int)(unsigned short)s) << 16;
  return v.f;
}
__device__ inline short f2b(float f) {
  union { float f; unsigned int u; } v; v.f = f;
  unsigned int r = (v.u + 0x7fffu + ((v.u >> 16) & 1u)) >> 16;
  return (short)r;
}
__device__ inline s16x8 pack8(float4 a, float4 b) {
  s16x8 r;
  r[0] = f2b(a.x); r[1] = f2b(a.y); r[2] = f2b(a.z); r[3] = f2b(a.w);
  r[4] = f2b(b.x); r[5] = f2b(b.y); r[6] = f2b(b.z); r[7] = f2b(b.w);
  return r;
}

__device__ inline f32x4 mfma16(s16x8 a, s16x8 b, f32x4 c) {
  return __builtin_amdgcn_mfma_f32_16x16x32_bf16(a, b, c, 0, 0, 0);
}

// ---------------- GEMM: C[M,N] = A[M,K] @ W[N,K]^T + bias, optional relu ---
// A: internal bf16. W, bias: external fp32 (converted to bf16 during staging).
// 128x128 tile, BK=32, 256 threads (4 waves, 2x2 of 64x64), mfma 16x16x32 bf16
template <int RELU>
__global__ void __launch_bounds__(256)
gemm_bt(const short* __restrict__ A, const float* __restrict__ W,
        const float* __restrict__ bias, short* __restrict__ C,
        int M, int N, int K) {
  __shared__ short As[128 * 32];
  __shared__ short Bs[128 * 32];
  const int tid  = threadIdx.x;
  const int lane = tid & 63;
  const int wave = tid >> 6;
  const int wr = (wave >> 1) << 6;   // wave row base (0/64)
  const int wc = (wave & 1) << 6;    // wave col base (0/64)
  const int ml = lane & 15;
  const int quad = lane >> 4;
  const int bm = blockIdx.y, bn = blockIdx.x;
  const int r0 = tid >> 2;           // staging row 0..63
  const int c0 = (tid & 3) << 3;     // staging col 0/8/16/24

  const short* Abase = A + (size_t)(bm * 128 + r0) * K + c0;
  const float* Wbase = W + (size_t)(bn * 128 + r0) * K + c0;
  f32x4 acc[4][4] = {};

  for (int k0 = 0; k0 < K; k0 += 32) {
    s16x8 ra0 = *(const s16x8*)(Abase + k0);
    s16x8 ra1 = *(const s16x8*)(Abase + (size_t)64 * K + k0);
    float4 w00 = *(const float4*)(Wbase + k0);
    float4 w01 = *(const float4*)(Wbase + k0 + 4);
    float4 w10 = *(const float4*)(Wbase + (size_t)64 * K + k0);
    float4 w11 = *(const float4*)(Wbase + (size_t)64 * K + k0 + 4);
    s16x8 rb0 = pack8(w00, w01);
    s16x8 rb1 = pack8(w10, w11);
    __syncthreads();   // protect previous iteration's LDS reads
    *(s16x8*)(As + r0 * 32 + c0) = ra0;
    *(s16x8*)(As + 2048 + r0 * 32 + c0) = ra1;
    *(s16x8*)(Bs + r0 * 32 + c0) = rb0;
    *(s16x8*)(Bs + 2048 + r0 * 32 + c0) = rb1;
    __syncthreads();
    s16x8 af[4], bfr[4];
#pragma unroll
    for (int i = 0; i < 4; ++i)
      af[i] = *(const s16x8*)(As + (wr + i * 16 + ml) * 32 + quad * 8);
#pragma unroll
    for (int j = 0; j < 4; ++j)
      bfr[j] = *(const s16x8*)(Bs + (wc + j * 16 + ml) * 32 + quad * 8);
#pragma unroll
    for (int i = 0; i < 4; ++i)
#pragma unroll
      for (int j = 0; j < 4; ++j)
        acc[i][j] = mfma16(af[i], bfr[j], acc[i][j]);
  }

#pragma unroll
  for (int j = 0; j < 4; ++j) {
    const int col = bn * 128 + wc + j * 16 + ml;
    const float bv = bias[col];
#pragma unroll
    for (int i = 0; i < 4; ++i) {
      const int row0 = bm * 128 + wr + i * 16 + quad * 4;
#pragma unroll
      for (int r = 0; r < 4; ++r) {
        float v = acc[i][j][r] + bv;
        if (RELU) v = fmaxf(v, 0.0f);
        C[(size_t)(row0 + r) * N + col] = f2b(v);
      }
    }
  }
}

// ---------------- fused attention (all-internal bf16) ----------------------
// one block per (b, h, q-tile of 32 rows). qkv layout (B,S,3D) bf16.
// pass A: QK^T -> exact fp32 per-row max; pass B: recompute (bit-identical),
// p=expf(s-max), P->bf16 LDS, row sums, V^T stage, PV MFMA.
__global__ void __launch_bounds__(256)
attn_kernel(const short* __restrict__ qkv, short* __restrict__ ctx) {
  __shared__ short KT[128 * 72];     // K tile [key][d], 18432 B
  __shared__ short VT[64 * 136];     // V^T tile [d][key], 17408 B
  __shared__ short Pt[32 * 136];     // P tile [qrow][key], 8704 B
  __shared__ float rmax2[2][2][16];  // [nh][mt][row16]
  __shared__ float lsum[32 * 8];
  const int tid = threadIdx.x;
  const int lane = tid & 63, wave = tid >> 6;
  const int ml = lane & 15, quad = lane >> 4;
  const int mt = wave & 1, nh = wave >> 1;   // nh in {0,1}
  const int bx = blockIdx.x;
  const int qt = bx & 15;
  const int bh = bx >> 4;
  const int b = bh >> 3, h = bh & 7;
  const size_t basebs = (size_t)b * 512 * 1536;
  const int hoff = h * 64;

  lsum[tid] = 0.f;  // 256 floats exactly; each thread later only touches slot tid

  s16x8 qf0, qf1;
  {
    const int qrow = qt * 32 + mt * 16 + ml;
    const short* qp = qkv + basebs + (size_t)qrow * 1536 + hoff;
    qf0 = *(const s16x8*)(qp + quad * 8);
    qf1 = *(const s16x8*)(qp + 32 + quad * 8);
  }

  // ---- pass A: exact row max ----
  f32x4 rmx = {-3e38f, -3e38f, -3e38f, -3e38f};
  for (int kt = 0; kt < 4; ++kt) {
#pragma unroll
    for (int i = 0; i < 4; ++i) {          // stage K tile: 128 keys x 64 d
      int u = i * 256 + tid;
      int key = u >> 3;
      int d8 = (u & 7) << 3;
      const short* kp = qkv + basebs + (size_t)(kt * 128 + key) * 1536 + 512 + hoff + d8;
      *(s16x8*)(KT + key * 72 + d8) = *(const s16x8*)kp;
    }
    __syncthreads();
#pragma unroll
    for (int nt = 0; nt < 4; ++nt) {
      const int nrow = nh * 64 + nt * 16 + ml;
      f32x4 sacc = {};
      s16x8 kf0 = *(const s16x8*)(KT + nrow * 72 + quad * 8);
      s16x8 kf1 = *(const s16x8*)(KT + nrow * 72 + 32 + quad * 8);
      sacc = mfma16(qf0, kf0, sacc);
      sacc = mfma16(qf1, kf1, sacc);
#pragma unroll
      for (int r = 0; r < 4; ++r)
        rmx[r] = fmaxf(rmx[r], sacc[r] * 0.125f);
    }
    __syncthreads();
  }
#pragma unroll
  for (int off = 1; off <= 8; off <<= 1) {
#pragma unroll
    for (int r = 0; r < 4; ++r)
      rmx[r] = fmaxf(rmx[r], __shfl_xor(rmx[r], off));
  }
  if (ml == 0) {
#pragma unroll
    for (int r = 0; r < 4; ++r)
      rmax2[nh][mt][quad * 4 + r] = rmx[r];
  }
  __syncthreads();
  float rm[4];
#pragma unroll
  for (int r = 0; r < 4; ++r)
    rm[r] = fmaxf(rmax2[0][mt][quad * 4 + r], rmax2[1][mt][quad * 4 + r]);

  // ---- pass B ----
  f32x4 oacc[2] = {};
  for (int kt = 0; kt < 4; ++kt) {
#pragma unroll
    for (int i = 0; i < 4; ++i) {          // stage K tile again
      int u = i * 256 + tid;
      int key = u >> 3;
      int d8 = (u & 7) << 3;
      const short* kp = qkv + basebs + (size_t)(kt * 128 + key) * 1536 + 512 + hoff + d8;
      *(s16x8*)(KT + key * 72 + d8) = *(const s16x8*)kp;
    }
    __syncthreads();   // KT visible; also fences prior iter's PV reads
#pragma unroll
    for (int nt = 0; nt < 4; ++nt) {
      const int nrow = nh * 64 + nt * 16 + ml;
      f32x4 sacc = {};
      s16x8 kf0 = *(const s16x8*)(KT + nrow * 72 + quad * 8);
      s16x8 kf1 = *(const s16x8*)(KT + nrow * 72 + 32 + quad * 8);
      sacc = mfma16(qf0, kf0, sacc);
      sacc = mfma16(qf1, kf1, sacc);
#pragma unroll
      for (int r = 0; r < 4; ++r) {
        float p = __expf(sacc[r] * 0.125f - rm[r]);   // arg <= 0
        Pt[(mt * 16 + quad * 4 + r) * 136 + nh * 64 + nt * 16 + ml] = f2b(p);
      }
    }
#pragma unroll
    for (int i = 0; i < 8; ++i) {          // stage V^T tile
      int u = i * 256 + tid;
      int kp = u >> 5;
      int dp = u & 31;
      const short* vp = qkv + basebs + (size_t)(kt * 128 + kp * 2) * 1536 + 1024 + hoff + dp * 2;
      unsigned int u0 = *(const unsigned int*)vp;
      unsigned int u1 = *(const unsigned int*)(vp + 1536);
      unsigned int w0 = (u0 & 0xffffu) | (u1 << 16);
      unsigned int w1 = (u0 >> 16) | (u1 & 0xffff0000u);
      *(unsigned int*)(VT + (dp * 2) * 136 + kp * 2) = w0;
      *(unsigned int*)(VT + (dp * 2 + 1) * 136 + kp * 2) = w1;
    }
    __syncthreads();   // Pt + VT visible
    {
      const int row = tid >> 3, seg = tid & 7;
      s16x8 p0 = *(const s16x8*)(Pt + row * 136 + seg * 16);
      s16x8 p1 = *(const s16x8*)(Pt + row * 136 + seg * 16 + 8);
      float s = 0.f;
#pragma unroll
      for (int e = 0; e < 8; ++e) s += b2f(p0[e]) + b2f(p1[e]);
      lsum[tid] += s;
    }
#pragma unroll
    for (int ks = 0; ks < 4; ++ks) {
      s16x8 pf = *(const s16x8*)(Pt + (mt * 16 + ml) * 136 + ks * 32 + quad * 8);
#pragma unroll
      for (int n2 = 0; n2 < 2; ++n2) {
        const int nd = (nh * 2 + n2) * 16 + ml;
        s16x8 vf = *(const s16x8*)(VT + nd * 136 + ks * 32 + quad * 8);
        oacc[n2] = mfma16(pf, vf, oacc[n2]);
      }
    }
  }
  __syncthreads();   // lsum complete

#pragma unroll
  for (int r = 0; r < 4; ++r) {
    const int srow = mt * 16 + quad * 4 + r;
    float l = 0.f;
#pragma unroll
    for (int s2 = 0; s2 < 8; ++s2) l += lsum[srow * 8 + s2];
    const float rl = 1.0f / l;
    const int grow = qt * 32 + srow;
#pragma unroll
    for (int n2 = 0; n2 < 2; ++n2) {
      const int d = (nh * 2 + n2) * 16 + ml;
      ctx[((size_t)b * 512 + grow) * 512 + hoff + d] = f2b(oacc[n2][r] * rl);
    }
  }
}

// ---------------- residual + layernorm (in-place on x, fp32 params) -------
__global__ void __launch_bounds__(256)
ln_kernel(short* __restrict__ x, const short* __restrict__ o,
          const float* __restrict__ g, const float* __restrict__ bta) {
  const int row = blockIdx.x * 4 + (threadIdx.x >> 6);
  const int lane = threadIdx.x & 63;
  short* xp = x + (size_t)row * 512 + lane * 8;
  const short* op = o + (size_t)row * 512 + lane * 8;
  s16x8 xv = *(const s16x8*)xp;
  s16x8 ov = *(const s16x8*)op;
  float v[8]; float s = 0.f, s2 = 0.f;
#pragma unroll
  for (int e = 0; e < 8; ++e) {
    float f = b2f(xv[e]) + b2f(ov[e]);
    v[e] = f; s += f; s2 += f * f;
  }
#pragma unroll
  for (int off = 32; off >= 1; off >>= 1) {
    s += __shfl_xor(s, off);
    s2 += __shfl_xor(s2, off);
  }
  const float mean = s * (1.f / 512.f);
  const float var = s2 * (1.f / 512.f) - mean * mean;
  const float rstd = rsqrtf(var + 1e-5f);
  float4 g0 = *(const float4*)(g + lane * 8);
  float4 g1 = *(const float4*)(g + lane * 8 + 4);
  float4 b0 = *(const float4*)(bta + lane * 8);
  float4 b1 = *(const float4*)(bta + lane * 8 + 4);
  float gv[8] = {g0.x, g0.y, g0.z, g0.w, g1.x, g1.y, g1.z, g1.w};
  float bv[8] = {b0.x, b0.y, b0.z, b0.w, b1.x, b1.y, b1.z, b1.w};
  s16x8 outv;
#pragma unroll
  for (int e = 0; e < 8; ++e)
    outv[e] = f2b((v[e] - mean) * rstd * gv[e] + bv[e]);
  *(s16x8*)xp = outv;
}

// ---------------- embed: x = (src @ inp_w^T + b) * sqrt(D) + PE -----------
// src, w, bias fp32; x bf16 out.
__global__ void __launch_bounds__(256)
embed_kernel(const float* __restrict__ src, const float* __restrict__ w,
             const float* __restrict__ bias, short* __restrict__ x) {
  const int row = blockIdx.x;   // b*512 + s
  const int s = row & 511;
  const int tid = threadIdx.x;
  __shared__ float sr[64];
  if (tid < 64) sr[tid] = src[(size_t)row * 64 + tid];
  __syncthreads();
#pragma unroll
  for (int rep = 0; rep < 2; ++rep) {
    const int n = tid + rep * 256;
    const float* wr = w + (size_t)n * 64;
    float acc = 0.f;
#pragma unroll
    for (int k8 = 0; k8 < 8; ++k8) {
      float4 wa = *(const float4*)(wr + k8 * 8);
      float4 wb = *(const float4*)(wr + k8 * 8 + 4);
      acc += sr[k8 * 8 + 0] * wa.x + sr[k8 * 8 + 1] * wa.y +
             sr[k8 * 8 + 2] * wa.z + sr[k8 * 8 + 3] * wa.w +
             sr[k8 * 8 + 4] * wb.x + sr[k8 * 8 + 5] * wb.y +
             sr[k8 * 8 + 6] * wb.z + sr[k8 * 8 + 7] * wb.w;
    }
    acc = (acc + bias[n]) * 22.62741699796952f;  // sqrt(512)
    const float ang = (float)s * expf((float)(n & ~1) * -0.0179889460390160f);
    acc += (n & 1) ? cosf(ang) : sinf(ang);
    x[(size_t)row * 512 + n] = f2b(acc);
  }
}

// ---------------- head: out[b] = w2 . relu(w1 @ x[b,-1] + b1) + b2 --------
// x bf16 internal; params + out fp32.
__global__ void __launch_bounds__(256)
head_kernel(const short* __restrict__ x, const float* __restrict__ w1,
            const float* __restrict__ b1, const float* __restrict__ w2,
            const float* __restrict__ b2, float* __restrict__ out) {
  const int b = blockIdx.x;
  const int tid = threadIdx.x;
  __shared__ float xl[512];
  __shared__ float red[256];
  for (int n = tid; n < 512; n += 256)
    xl[n] = b2f(x[((size_t)b * 512 + 511) * 512 + n]);
  __syncthreads();
  float acc = 0.f;
#pragma unroll
  for (int rep = 0; rep < 8; ++rep) {
    const int f = tid + rep * 256;
    const float* wr = w1 + (size_t)f * 512;
    float hv = 0.f;
    for (int k8 = 0; k8 < 64; ++k8) {
      float4 wa = *(const float4*)(wr + k8 * 8);
      float4 wb = *(const float4*)(wr + k8 * 8 + 4);
      hv += xl[k8 * 8 + 0] * wa.x + xl[k8 * 8 + 1] * wa.y +
            xl[k8 * 8 + 2] * wa.z + xl[k8 * 8 + 3] * wa.w +
            xl[k8 * 8 + 4] * wb.x + xl[k8 * 8 + 5] * wb.y +
            xl[k8 * 8 + 6] * wb.z + xl[k8 * 8 + 7] * wb.w;
    }
    hv += b1[f];
    hv = fmaxf(hv, 0.f);
    acc += hv * w2[f];
  }
  red[tid] = acc;
  __syncthreads();
  for (int stride = 128; stride > 0; stride >>= 1) {
    if (tid < stride) red[tid] += red[tid + stride];
    __syncthreads();
  }
  if (tid == 0) out[b] = red[0] + b2[0];
}

extern "C" void kernel_launch(void* const* d_in, const int* in_sizes, int n_in,
                              void* d_out, int out_size, void* d_ws, size_t ws_size,
                              hipStream_t stream) {
  (void)in_sizes; (void)n_in; (void)out_size; (void)ws_size;
  const float* src       = (const float*)d_in[0];
  const float* inp_w     = (const float*)d_in[1];
  const float* inp_b     = (const float*)d_in[2];
  const float* in_proj_w = (const float*)d_in[3];
  const float* in_proj_b = (const float*)d_in[4];
  const float* out_w     = (const float*)d_in[5];
  const float* out_b     = (const float*)d_in[6];
  const float* ff_w1     = (const float*)d_in[7];
  const float* ff_b1     = (const float*)d_in[8];
  const float* ff_w2     = (const float*)d_in[9];
  const float* ff_b2     = (const float*)d_in[10];
  const float* ln1_g     = (const float*)d_in[11];
  const float* ln1_b     = (const float*)d_in[12];
  const float* ln2_g     = (const float*)d_in[13];
  const float* ln2_b     = (const float*)d_in[14];
  const float* op_w1     = (const float*)d_in[15];
  const float* op_b1     = (const float*)d_in[16];
  const float* op_w2     = (const float*)d_in[17];
  const float* op_b2     = (const float*)d_in[18];

  short* ws   = (short*)d_ws;
  short* x    = ws;                   //  8,388,608 elems (bf16)
  short* qkv  = ws + 8388608;         // 25,165,824 elems
  short* ctx  = qkv + 25165824;       //  8,388,608 elems
  short* obuf = ctx + 8388608;        //  8,388,608 elems
  short* h    = qkv;                  // FF hidden reuses qkv+ctx (33,554,432)

  embed_kernel<<<16384, 256, 0, stream>>>(src, inp_w, inp_b, x);
  for (int l = 0; l < 6; ++l) {
    gemm_bt<0><<<dim3(12, 128), 256, 0, stream>>>(
        x, in_proj_w + (size_t)l * 1536 * 512, in_proj_b + l * 1536, qkv,
        16384, 1536, 512);
    attn_kernel<<<4096, 256, 0, stream>>>(qkv, ctx);
    gemm_bt<0><<<dim3(4, 128), 256, 0, stream>>>(
        ctx, out_w + (size_t)l * 512 * 512, out_b + l * 512, obuf,
        16384, 512, 512);
    ln_kernel<<<4096, 256, 0, stream>>>(x, obuf, ln1_g + l * 512, ln1_b + l * 512);
    gemm_bt<1><<<dim3(16, 128), 256, 0, stream>>>(
        x, ff_w1 + (size_t)l * 2048 * 512, ff_b1 + l * 2048, h,
        16384, 2048, 512);
    gemm_bt<0><<<dim3(4, 128), 256, 0, stream>>>(
        h, ff_w2 + (size_t)l * 512 * 2048, ff_b2 + l * 512, obuf,
        16384, 512, 2048);
    ln_kernel<<<4096, 256, 0, stream>>>(x, obuf, ln2_g + l * 512, ln2_b + l * 512);
  }
  head_kernel<<<32, 256, 0, stream>>>(x, op_w1, op_b1, op_w2, op_b2, (float*)d_out);
}

// Round 5
// 1904.685 us; speedup vs baseline: 1.3125x; 1.3125x over previous
//
#include <hip/hip_runtime.h>

typedef short s16x8 __attribute__((ext_vector_type(8)));
typedef float f32x4 __attribute__((ext_vector_type(4)));

// device-global scratch (outside d_ws; fully rewritten every launch)
__device__ short g_wbuf[3145728];   // per-layer bf16 weights: inproj|outw|ffw1|ffw2
__device__ short g_srcb[1048576];   // src as bf16 (16384 x 64)
__device__ short g_inpwb[32768];    // inp_w as bf16 (512 x 64)
__device__ float g_pe[262144];      // positional encoding (512 x 512)
__device__ float g_hpart[256];      // head partials

__device__ inline float b2f(short s) {
  union { unsigned int u; float f; } v;
  v.u = ((unsigned int)(unsigned short)s) << 16;
  return v.f;
}
__device__ inline short f2b(float f) {
  union { float f; unsigned int u; } v; v.f = f;
  unsigned int r = (v.u + 0x7fffu + ((v.u >> 16) & 1u)) >> 16;
  return (short)r;
}
__device__ inline s16x8 pack8(float4 a, float4 b) {
  s16x8 r;
  r[0] = f2b(a.x); r[1] = f2b(a.y); r[2] = f2b(a.z); r[3] = f2b(a.w);
  r[4] = f2b(b.x); r[5] = f2b(b.y); r[6] = f2b(b.z); r[7] = f2b(b.w);
  return r;
}

__device__ inline f32x4 mfma16(s16x8 a, s16x8 b, f32x4 c) {
  return __builtin_amdgcn_mfma_f32_16x16x32_bf16(a, b, c, 0, 0, 0);
}

typedef const __attribute__((address_space(1))) void* as1cptr;
typedef __attribute__((address_space(3))) void* as3ptr;
__device__ inline void gl2lds16(const short* g, short* l) {
  __builtin_amdgcn_global_load_lds((as1cptr)g, (as3ptr)l, 16, 0, 0);
}

// ---------------- fp32 -> bf16 conversion kernels --------------------------
// cvt2: src (16384x64 -> g_srcb, 512 blocks) + inp_w (512x64 -> g_inpwb, 16)
__global__ void __launch_bounds__(256)
cvt2_kernel(const float* __restrict__ i0, const float* __restrict__ i1) {
  const int b = blockIdx.x;
  const float* src; short* dst; int base;
  if (b < 512) { src = i0; dst = g_srcb; base = b; }
  else         { src = i1; dst = g_inpwb; base = b - 512; }
  const int idx = (base * 256 + threadIdx.x) * 8;
  float4 a = *(const float4*)(src + idx);
  float4 c = *(const float4*)(src + idx + 4);
  *(s16x8*)(dst + idx) = pack8(a, c);
}

// cvt4: one layer's weights into g_wbuf. blocks: 384|128|512|512 = 1536
__global__ void __launch_bounds__(256)
cvt4_kernel(const float* __restrict__ i0, const float* __restrict__ i1,
            const float* __restrict__ i2, const float* __restrict__ i3) {
  const int b = blockIdx.x;
  const float* src; short* dst; int base;
  if (b < 384)       { src = i0; dst = g_wbuf;           base = b; }
  else if (b < 512)  { src = i1; dst = g_wbuf +  786432; base = b - 384; }
  else if (b < 1024) { src = i2; dst = g_wbuf + 1048576; base = b - 512; }
  else               { src = i3; dst = g_wbuf + 2097152; base = b - 1024; }
  const int idx = (base * 256 + threadIdx.x) * 8;
  float4 a = *(const float4*)(src + idx);
  float4 c = *(const float4*)(src + idx + 4);
  *(s16x8*)(dst + idx) = pack8(a, c);
}

// ---------------- PE table: g_pe[s][n] ------------------------------------
__global__ void __launch_bounds__(256)
pe_kernel() {
  const int s = blockIdx.x;
  const int n0 = threadIdx.x * 2;
  const float ang = (float)s * expf((float)n0 * -0.0179889460390160f);
  g_pe[s * 512 + n0]     = sinf(ang);
  g_pe[s * 512 + n0 + 1] = cosf(ang);
}

// ---------------- GEMM: C[M,N] = A[M,K] @ W[N,K]^T + epilogue -------------
// All-bf16, m97 structure: 128x128 tile, BK=32, global_load_lds width=16.
// EPI: 0 = +bias; 1 = relu(+bias); 2 = embed ((acc+bias)*sqrt512 + PE),
//      EPI==2 uses A=g_srcb, W=g_inpwb (symbols; Ain/woff ignored).
template <int EPI>
__global__ void __launch_bounds__(256)
gemm_bt(const short* __restrict__ Ain, int woff, const float* __restrict__ bias,
        short* __restrict__ C, int M, int N, int K) {
  __shared__ short As[128 * 32];
  __shared__ short Bs[128 * 32];
  const int tid  = threadIdx.x;
  const int lane = tid & 63;
  const int wave = tid >> 6;
  const int wr = (wave >> 1) << 6;
  const int wc = (wave & 1) << 6;
  const int ml = lane & 15;
  const int quad = lane >> 4;
  const int bm = blockIdx.y, bn = blockIdx.x;
  const int r0 = tid >> 2;
  const int c0 = (tid & 3) << 3;

  const short* A = (EPI == 2) ? (const short*)g_srcb : Ain;
  const short* W = (EPI == 2) ? (const short*)g_inpwb : (const short*)(g_wbuf + woff);
  const short* Abase = A + (size_t)(bm * 128 + r0) * K + c0;
  const short* Wbase = W + (size_t)(bn * 128 + r0) * K + c0;
  f32x4 acc[4][4] = {};

  for (int k0 = 0; k0 < K; k0 += 32) {
    gl2lds16(Abase + k0, As + tid * 8);
    gl2lds16(Abase + (size_t)64 * K + k0, As + 2048 + tid * 8);
    gl2lds16(Wbase + k0, Bs + tid * 8);
    gl2lds16(Wbase + (size_t)64 * K + k0, Bs + 2048 + tid * 8);
    __syncthreads();
    s16x8 af[4], bfr[4];
#pragma unroll
    for (int i = 0; i < 4; ++i)
      af[i] = *(const s16x8*)(As + (wr + i * 16 + ml) * 32 + quad * 8);
#pragma unroll
    for (int j = 0; j < 4; ++j)
      bfr[j] = *(const s16x8*)(Bs + (wc + j * 16 + ml) * 32 + quad * 8);
#pragma unroll
    for (int i = 0; i < 4; ++i)
#pragma unroll
      for (int j = 0; j < 4; ++j)
        acc[i][j] = mfma16(af[i], bfr[j], acc[i][j]);
    __syncthreads();
  }

#pragma unroll
  for (int j = 0; j < 4; ++j) {
    const int col = bn * 128 + wc + j * 16 + ml;
    const float bv = bias[col];
#pragma unroll
    for (int i = 0; i < 4; ++i) {
      const int row0 = bm * 128 + wr + i * 16 + quad * 4;
#pragma unroll
      for (int r = 0; r < 4; ++r) {
        float v = acc[i][j][r] + bv;
        if (EPI == 1) v = fmaxf(v, 0.0f);
        if (EPI == 2) {
          const int s = (row0 + r) & 511;
          v = (acc[i][j][r] + bv) * 22.62741699796952f + g_pe[s * 512 + col];
        }
        C[(size_t)(row0 + r) * N + col] = f2b(v);
      }
    }
  }
}

// ---------------- fused attention (unchanged from R4, verified) -----------
__global__ void __launch_bounds__(256)
attn_kernel(const short* __restrict__ qkv, short* __restrict__ ctx) {
  __shared__ short KT[128 * 72];
  __shared__ short VT[64 * 136];
  __shared__ short Pt[32 * 136];
  __shared__ float rmax2[2][2][16];
  __shared__ float lsum[32 * 8];
  const int tid = threadIdx.x;
  const int lane = tid & 63, wave = tid >> 6;
  const int ml = lane & 15, quad = lane >> 4;
  const int mt = wave & 1, nh = wave >> 1;
  const int bx = blockIdx.x;
  const int qt = bx & 15;
  const int bh = bx >> 4;
  const int b = bh >> 3, h = bh & 7;
  const size_t basebs = (size_t)b * 512 * 1536;
  const int hoff = h * 64;

  lsum[tid] = 0.f;

  s16x8 qf0, qf1;
  {
    const int qrow = qt * 32 + mt * 16 + ml;
    const short* qp = qkv + basebs + (size_t)qrow * 1536 + hoff;
    qf0 = *(const s16x8*)(qp + quad * 8);
    qf1 = *(const s16x8*)(qp + 32 + quad * 8);
  }

  // pass A: exact row max
  f32x4 rmx = {-3e38f, -3e38f, -3e38f, -3e38f};
  for (int kt = 0; kt < 4; ++kt) {
#pragma unroll
    for (int i = 0; i < 4; ++i) {
      int u = i * 256 + tid;
      int key = u >> 3;
      int d8 = (u & 7) << 3;
      const short* kp = qkv + basebs + (size_t)(kt * 128 + key) * 1536 + 512 + hoff + d8;
      *(s16x8*)(KT + key * 72 + d8) = *(const s16x8*)kp;
    }
    __syncthreads();
#pragma unroll
    for (int nt = 0; nt < 4; ++nt) {
      const int nrow = nh * 64 + nt * 16 + ml;
      f32x4 sacc = {};
      s16x8 kf0 = *(const s16x8*)(KT + nrow * 72 + quad * 8);
      s16x8 kf1 = *(const s16x8*)(KT + nrow * 72 + 32 + quad * 8);
      sacc = mfma16(qf0, kf0, sacc);
      sacc = mfma16(qf1, kf1, sacc);
#pragma unroll
      for (int r = 0; r < 4; ++r)
        rmx[r] = fmaxf(rmx[r], sacc[r] * 0.125f);
    }
    __syncthreads();
  }
#pragma unroll
  for (int off = 1; off <= 8; off <<= 1) {
#pragma unroll
    for (int r = 0; r < 4; ++r)
      rmx[r] = fmaxf(rmx[r], __shfl_xor(rmx[r], off));
  }
  if (ml == 0) {
#pragma unroll
    for (int r = 0; r < 4; ++r)
      rmax2[nh][mt][quad * 4 + r] = rmx[r];
  }
  __syncthreads();
  float rm[4];
#pragma unroll
  for (int r = 0; r < 4; ++r)
    rm[r] = fmaxf(rmax2[0][mt][quad * 4 + r], rmax2[1][mt][quad * 4 + r]);

  // pass B
  f32x4 oacc[2] = {};
  for (int kt = 0; kt < 4; ++kt) {
#pragma unroll
    for (int i = 0; i < 4; ++i) {
      int u = i * 256 + tid;
      int key = u >> 3;
      int d8 = (u & 7) << 3;
      const short* kp = qkv + basebs + (size_t)(kt * 128 + key) * 1536 + 512 + hoff + d8;
      *(s16x8*)(KT + key * 72 + d8) = *(const s16x8*)kp;
    }
    __syncthreads();
#pragma unroll
    for (int nt = 0; nt < 4; ++nt) {
      const int nrow = nh * 64 + nt * 16 + ml;
      f32x4 sacc = {};
      s16x8 kf0 = *(const s16x8*)(KT + nrow * 72 + quad * 8);
      s16x8 kf1 = *(const s16x8*)(KT + nrow * 72 + 32 + quad * 8);
      sacc = mfma16(qf0, kf0, sacc);
      sacc = mfma16(qf1, kf1, sacc);
#pragma unroll
      for (int r = 0; r < 4; ++r) {
        float p = __expf(sacc[r] * 0.125f - rm[r]);
        Pt[(mt * 16 + quad * 4 + r) * 136 + nh * 64 + nt * 16 + ml] = f2b(p);
      }
    }
#pragma unroll
    for (int i = 0; i < 8; ++i) {
      int u = i * 256 + tid;
      int kp = u >> 5;
      int dp = u & 31;
      const short* vp = qkv + basebs + (size_t)(kt * 128 + kp * 2) * 1536 + 1024 + hoff + dp * 2;
      unsigned int u0 = *(const unsigned int*)vp;
      unsigned int u1 = *(const unsigned int*)(vp + 1536);
      unsigned int w0 = (u0 & 0xffffu) | (u1 << 16);
      unsigned int w1 = (u0 >> 16) | (u1 & 0xffff0000u);
      *(unsigned int*)(VT + (dp * 2) * 136 + kp * 2) = w0;
      *(unsigned int*)(VT + (dp * 2 + 1) * 136 + kp * 2) = w1;
    }
    __syncthreads();
    {
      const int row = tid >> 3, seg = tid & 7;
      s16x8 p0 = *(const s16x8*)(Pt + row * 136 + seg * 16);
      s16x8 p1 = *(const s16x8*)(Pt + row * 136 + seg * 16 + 8);
      float s = 0.f;
#pragma unroll
      for (int e = 0; e < 8; ++e) s += b2f(p0[e]) + b2f(p1[e]);
      lsum[tid] += s;
    }
#pragma unroll
    for (int ks = 0; ks < 4; ++ks) {
      s16x8 pf = *(const s16x8*)(Pt + (mt * 16 + ml) * 136 + ks * 32 + quad * 8);
#pragma unroll
      for (int n2 = 0; n2 < 2; ++n2) {
        const int nd = (nh * 2 + n2) * 16 + ml;
        s16x8 vf = *(const s16x8*)(VT + nd * 136 + ks * 32 + quad * 8);
        oacc[n2] = mfma16(pf, vf, oacc[n2]);
      }
    }
  }
  __syncthreads();

#pragma unroll
  for (int r = 0; r < 4; ++r) {
    const int srow = mt * 16 + quad * 4 + r;
    float l = 0.f;
#pragma unroll
    for (int s2 = 0; s2 < 8; ++s2) l += lsum[srow * 8 + s2];
    const float rl = 1.0f / l;
    const int grow = qt * 32 + srow;
#pragma unroll
    for (int n2 = 0; n2 < 2; ++n2) {
      const int d = (nh * 2 + n2) * 16 + ml;
      ctx[((size_t)b * 512 + grow) * 512 + hoff + d] = f2b(oacc[n2][r] * rl);
    }
  }
}

// ---------------- residual + layernorm (in-place on x, fp32 params) -------
__global__ void __launch_bounds__(256)
ln_kernel(short* __restrict__ x, const short* __restrict__ o,
          const float* __restrict__ g, const float* __restrict__ bta) {
  const int row = blockIdx.x * 4 + (threadIdx.x >> 6);
  const int lane = threadIdx.x & 63;
  short* xp = x + (size_t)row * 512 + lane * 8;
  const short* op = o + (size_t)row * 512 + lane * 8;
  s16x8 xv = *(const s16x8*)xp;
  s16x8 ov = *(const s16x8*)op;
  float v[8]; float s = 0.f, s2 = 0.f;
#pragma unroll
  for (int e = 0; e < 8; ++e) {
    float f = b2f(xv[e]) + b2f(ov[e]);
    v[e] = f; s += f; s2 += f * f;
  }
#pragma unroll
  for (int off = 32; off >= 1; off >>= 1) {
    s += __shfl_xor(s, off);
    s2 += __shfl_xor(s2, off);
  }
  const float mean = s * (1.f / 512.f);
  const float var = s2 * (1.f / 512.f) - mean * mean;
  const float rstd = rsqrtf(var + 1e-5f);
  float4 g0 = *(const float4*)(g + lane * 8);
  float4 g1 = *(const float4*)(g + lane * 8 + 4);
  float4 b0 = *(const float4*)(bta + lane * 8);
  float4 b1 = *(const float4*)(bta + lane * 8 + 4);
  float gv[8] = {g0.x, g0.y, g0.z, g0.w, g1.x, g1.y, g1.z, g1.w};
  float bv[8] = {b0.x, b0.y, b0.z, b0.w, b1.x, b1.y, b1.z, b1.w};
  s16x8 outv;
#pragma unroll
  for (int e = 0; e < 8; ++e)
    outv[e] = f2b((v[e] - mean) * rstd * gv[e] + bv[e]);
  *(s16x8*)xp = outv;
}

// ---------------- head, stage 1: 256 blocks of (b, feature-seg) ------------
__global__ void __launch_bounds__(256)
head1_kernel(const short* __restrict__ x, const float* __restrict__ w1,
             const float* __restrict__ b1, const float* __restrict__ w2) {
  const int bidx = blockIdx.x;
  const int b = bidx >> 3, seg = bidx & 7;
  const int tid = threadIdx.x;
  __shared__ float xl[512];
  __shared__ float red[256];
  for (int n = tid; n < 512; n += 256)
    xl[n] = b2f(x[((size_t)b * 512 + 511) * 512 + n]);
  __syncthreads();
  const int f = seg * 256 + tid;
  const float* wr = w1 + (size_t)f * 512;
  float hv = 0.f;
  for (int k8 = 0; k8 < 64; ++k8) {
    float4 wa = *(const float4*)(wr + k8 * 8);
    float4 wb = *(const float4*)(wr + k8 * 8 + 4);
    hv += xl[k8 * 8 + 0] * wa.x + xl[k8 * 8 + 1] * wa.y +
          xl[k8 * 8 + 2] * wa.z + xl[k8 * 8 + 3] * wa.w +
          xl[k8 * 8 + 4] * wb.x + xl[k8 * 8 + 5] * wb.y +
          xl[k8 * 8 + 6] * wb.z + xl[k8 * 8 + 7] * wb.w;
  }
  hv += b1[f];
  hv = fmaxf(hv, 0.f);
  red[tid] = hv * w2[f];
  __syncthreads();
  for (int stride = 128; stride > 0; stride >>= 1) {
    if (tid < stride) red[tid] += red[tid + stride];
    __syncthreads();
  }
  if (tid == 0) g_hpart[bidx] = red[0];
}

__global__ void __launch_bounds__(64)
head2_kernel(const float* __restrict__ b2, float* __restrict__ out) {
  const int t = threadIdx.x;
  if (t < 32) {
    float s = 0.f;
#pragma unroll
    for (int c = 0; c < 8; ++c) s += g_hpart[t * 8 + c];
    out[t] = s + b2[0];
  }
}

extern "C" void kernel_launch(void* const* d_in, const int* in_sizes, int n_in,
                              void* d_out, int out_size, void* d_ws, size_t ws_size,
                              hipStream_t stream) {
  (void)in_sizes; (void)n_in; (void)out_size; (void)ws_size;
  const float* src       = (const float*)d_in[0];
  const float* inp_w     = (const float*)d_in[1];
  const float* inp_b     = (const float*)d_in[2];
  const float* in_proj_w = (const float*)d_in[3];
  const float* in_proj_b = (const float*)d_in[4];
  const float* out_w     = (const float*)d_in[5];
  const float* out_b     = (const float*)d_in[6];
  const float* ff_w1     = (const float*)d_in[7];
  const float* ff_b1     = (const float*)d_in[8];
  const float* ff_w2     = (const float*)d_in[9];
  const float* ff_b2     = (const float*)d_in[10];
  const float* ln1_g     = (const float*)d_in[11];
  const float* ln1_b     = (const float*)d_in[12];
  const float* ln2_g     = (const float*)d_in[13];
  const float* ln2_b     = (const float*)d_in[14];
  const float* op_w1     = (const float*)d_in[15];
  const float* op_b1     = (const float*)d_in[16];
  const float* op_w2     = (const float*)d_in[17];
  const float* op_b2     = (const float*)d_in[18];

  short* ws   = (short*)d_ws;                    // R4-identical layout, 100.7 MB
  short* x    = ws;                              //  8,388,608
  short* qkv  = ws + 8388608;                    // 25,165,824
  short* ctx  = qkv + 25165824;                  //  8,388,608
  short* obuf = ctx + 8388608;                   //  8,388,608
  short* h    = qkv;                             // ff hidden spans qkv+ctx

  cvt2_kernel<<<528, 256, 0, stream>>>(src, inp_w);
  pe_kernel<<<512, 256, 0, stream>>>();
  gemm_bt<2><<<dim3(4, 128), 256, 0, stream>>>(nullptr, 0, inp_b, x, 16384, 512, 64);

  for (int l = 0; l < 6; ++l) {
    cvt4_kernel<<<1536, 256, 0, stream>>>(
        in_proj_w + (size_t)l * 786432, out_w + (size_t)l * 262144,
        ff_w1 + (size_t)l * 1048576, ff_w2 + (size_t)l * 1048576);
    gemm_bt<0><<<dim3(12, 128), 256, 0, stream>>>(
        x, 0, in_proj_b + l * 1536, qkv, 16384, 1536, 512);
    attn_kernel<<<4096, 256, 0, stream>>>(qkv, ctx);
    gemm_bt<0><<<dim3(4, 128), 256, 0, stream>>>(
        ctx, 786432, out_b + l * 512, obuf, 16384, 512, 512);
    ln_kernel<<<4096, 256, 0, stream>>>(x, obuf, ln1_g + l * 512, ln1_b + l * 512);
    gemm_bt<1><<<dim3(16, 128), 256, 0, stream>>>(
        x, 1048576, ff_b1 + l * 2048, h, 16384, 2048, 512);
    gemm_bt<0><<<dim3(4, 128), 256, 0, stream>>>(
        h, 2097152, ff_b2 + l * 512, obuf, 16384, 512, 2048);
    ln_kernel<<<4096, 256, 0, stream>>>(x, obuf, ln2_g + l * 512, ln2_b + l * 512);
  }
  head1_kernel<<<256, 256, 0, stream>>>(x, op_w1, op_b1, op_w2);
  head2_kernel<<<1, 64, 0, stream>>>(op_b2, (float*)d_out);
}

// Round 6
// 1791.485 us; speedup vs baseline: 1.3954x; 1.0632x over previous
//
#include <hip/hip_runtime.h>

typedef short s16x8 __attribute__((ext_vector_type(8)));
typedef float f32x4 __attribute__((ext_vector_type(4)));

// device-global scratch (outside d_ws; fully rewritten every launch)
__device__ short g_wbuf[3145728];   // per-layer bf16 weights: inproj|outw|ffw1|ffw2
__device__ short g_srcb[1048576];   // src as bf16 (16384 x 64)
__device__ short g_inpwb[32768];    // inp_w as bf16 (512 x 64)
__device__ float g_pe[262144];      // positional encoding (512 x 512)
__device__ float g_hpart[256];      // head partials

__device__ inline float b2f(short s) {
  union { unsigned int u; float f; } v;
  v.u = ((unsigned int)(unsigned short)s) << 16;
  return v.f;
}
__device__ inline short f2b(float f) {
  union { float f; unsigned int u; } v; v.f = f;
  unsigned int r = (v.u + 0x7fffu + ((v.u >> 16) & 1u)) >> 16;
  return (short)r;
}
__device__ inline s16x8 pack8(float4 a, float4 b) {
  s16x8 r;
  r[0] = f2b(a.x); r[1] = f2b(a.y); r[2] = f2b(a.z); r[3] = f2b(a.w);
  r[4] = f2b(b.x); r[5] = f2b(b.y); r[6] = f2b(b.z); r[7] = f2b(b.w);
  return r;
}

__device__ inline f32x4 mfma16(s16x8 a, s16x8 b, f32x4 c) {
  return __builtin_amdgcn_mfma_f32_16x16x32_bf16(a, b, c, 0, 0, 0);
}

typedef const __attribute__((address_space(1))) void* as1cptr;
typedef __attribute__((address_space(3))) void* as3ptr;
__device__ inline void gl2lds16(const short* g, short* l) {
  __builtin_amdgcn_global_load_lds((as1cptr)g, (as3ptr)l, 16, 0, 0);
}

// ---------------- fp32 -> bf16 conversion kernels --------------------------
__global__ void __launch_bounds__(256)
cvt2_kernel(const float* __restrict__ i0, const float* __restrict__ i1) {
  const int b = blockIdx.x;
  const float* src; short* dst; int base;
  if (b < 512) { src = i0; dst = g_srcb; base = b; }
  else         { src = i1; dst = g_inpwb; base = b - 512; }
  const int idx = (base * 256 + threadIdx.x) * 8;
  float4 a = *(const float4*)(src + idx);
  float4 c = *(const float4*)(src + idx + 4);
  *(s16x8*)(dst + idx) = pack8(a, c);
}

__global__ void __launch_bounds__(256)
cvt4_kernel(const float* __restrict__ i0, const float* __restrict__ i1,
            const float* __restrict__ i2, const float* __restrict__ i3) {
  const int b = blockIdx.x;
  const float* src; short* dst; int base;
  if (b < 384)       { src = i0; dst = g_wbuf;           base = b; }
  else if (b < 512)  { src = i1; dst = g_wbuf +  786432; base = b - 384; }
  else if (b < 1024) { src = i2; dst = g_wbuf + 1048576; base = b - 512; }
  else               { src = i3; dst = g_wbuf + 2097152; base = b - 1024; }
  const int idx = (base * 256 + threadIdx.x) * 8;
  float4 a = *(const float4*)(src + idx);
  float4 c = *(const float4*)(src + idx + 4);
  *(s16x8*)(dst + idx) = pack8(a, c);
}

// ---------------- PE table: g_pe[s][n] ------------------------------------
__global__ void __launch_bounds__(256)
pe_kernel() {
  const int s = blockIdx.x;
  const int n0 = threadIdx.x * 2;
  const float ang = (float)s * expf((float)n0 * -0.0179889460390160f);
  g_pe[s * 512 + n0]     = sinf(ang);
  g_pe[s * 512 + n0 + 1] = cosf(ang);
}

// ---------------- GEMM: C[M,N] = A[M,K] @ W[N,K]^T + epilogue -------------
// EPI: 0 = +bias; 1 = relu(+bias); 2 = embed ((acc+bias)*sqrt512 + PE)
template <int EPI>
__global__ void __launch_bounds__(256)
gemm_bt(const short* __restrict__ Ain, int woff, const float* __restrict__ bias,
        short* __restrict__ C, int M, int N, int K) {
  __shared__ short As[128 * 32];
  __shared__ short Bs[128 * 32];
  const int tid  = threadIdx.x;
  const int lane = tid & 63;
  const int wave = tid >> 6;
  const int wr = (wave >> 1) << 6;
  const int wc = (wave & 1) << 6;
  const int ml = lane & 15;
  const int quad = lane >> 4;
  const int bm = blockIdx.y, bn = blockIdx.x;
  const int r0 = tid >> 2;
  const int c0 = (tid & 3) << 3;

  const short* A = (EPI == 2) ? (const short*)g_srcb : Ain;
  const short* W = (EPI == 2) ? (const short*)g_inpwb : (const short*)(g_wbuf + woff);
  const short* Abase = A + (size_t)(bm * 128 + r0) * K + c0;
  const short* Wbase = W + (size_t)(bn * 128 + r0) * K + c0;
  f32x4 acc[4][4] = {};

  for (int k0 = 0; k0 < K; k0 += 32) {
    gl2lds16(Abase + k0, As + tid * 8);
    gl2lds16(Abase + (size_t)64 * K + k0, As + 2048 + tid * 8);
    gl2lds16(Wbase + k0, Bs + tid * 8);
    gl2lds16(Wbase + (size_t)64 * K + k0, Bs + 2048 + tid * 8);
    __syncthreads();
    s16x8 af[4], bfr[4];
#pragma unroll
    for (int i = 0; i < 4; ++i)
      af[i] = *(const s16x8*)(As + (wr + i * 16 + ml) * 32 + quad * 8);
#pragma unroll
    for (int j = 0; j < 4; ++j)
      bfr[j] = *(const s16x8*)(Bs + (wc + j * 16 + ml) * 32 + quad * 8);
#pragma unroll
    for (int i = 0; i < 4; ++i)
#pragma unroll
      for (int j = 0; j < 4; ++j)
        acc[i][j] = mfma16(af[i], bfr[j], acc[i][j]);
    __syncthreads();
  }

#pragma unroll
  for (int j = 0; j < 4; ++j) {
    const int col = bn * 128 + wc + j * 16 + ml;
    const float bv = bias[col];
#pragma unroll
    for (int i = 0; i < 4; ++i) {
      const int row0 = bm * 128 + wr + i * 16 + quad * 4;
#pragma unroll
      for (int r = 0; r < 4; ++r) {
        float v = acc[i][j][r] + bv;
        if (EPI == 1) v = fmaxf(v, 0.0f);
        if (EPI == 2) {
          const int s = (row0 + r) & 511;
          v = (acc[i][j][r] + bv) * 22.62741699796952f + g_pe[s * 512 + col];
        }
        C[(size_t)(row0 + r) * N + col] = f2b(v);
      }
    }
  }
}

// ---------------- fused attention, single pass ----------------------------
// block id: qt = bx>>8 (slow), bh = bx&255 (fast) -> blocks sharing (b,h) K/V
// land on the same XCD (round-robin), maximizing L2 reuse.
// Scores held in registers (4kt x 4nt x f32x4 = 64 VGPRs): exact max, exp,
// in-register row sums; P->bf16 LDS only for the PV MFMA A-operand.
__global__ void __launch_bounds__(256, 3)
attn_kernel(const short* __restrict__ qkv, short* __restrict__ ctx) {
  __shared__ short KT[128 * 72];     // 18432 B
  __shared__ short VT[64 * 136];     // 17408 B
  __shared__ short Pt[32 * 136];     // 8704 B
  __shared__ float rcomb[2][2][16];  // [nh][mt][row16]: max, then sums
  const int tid = threadIdx.x;
  const int lane = tid & 63, wave = tid >> 6;
  const int ml = lane & 15, quad = lane >> 4;
  const int mt = wave & 1, nh = wave >> 1;
  const int bx = blockIdx.x;
  const int qt = bx >> 8;
  const int bh = bx & 255;
  const int b = bh >> 3, h = bh & 7;
  const size_t basebs = (size_t)b * 512 * 1536;
  const int hoff = h * 64;

  s16x8 qf0, qf1;
  {
    const int qrow = qt * 32 + mt * 16 + ml;
    const short* qp = qkv + basebs + (size_t)qrow * 1536 + hoff;
    qf0 = *(const s16x8*)(qp + quad * 8);
    qf1 = *(const s16x8*)(qp + 32 + quad * 8);
  }

  // ---- phase 1: all scores into registers ----
  f32x4 sc[4][4];
#pragma unroll
  for (int kt = 0; kt < 4; ++kt) {
#pragma unroll
    for (int i = 0; i < 4; ++i) {          // stage K tile: 128 keys x 64 d
      int u = i * 256 + tid;
      int key = u >> 3;
      int d8 = (u & 7) << 3;
      const short* kp = qkv + basebs + (size_t)(kt * 128 + key) * 1536 + 512 + hoff + d8;
      *(s16x8*)(KT + key * 72 + d8) = *(const s16x8*)kp;
    }
    __syncthreads();
#pragma unroll
    for (int nt = 0; nt < 4; ++nt) {
      const int nrow = nh * 64 + nt * 16 + ml;
      f32x4 sacc = {};
      s16x8 kf0 = *(const s16x8*)(KT + nrow * 72 + quad * 8);
      s16x8 kf1 = *(const s16x8*)(KT + nrow * 72 + 32 + quad * 8);
      sacc = mfma16(qf0, kf0, sacc);
      sacc = mfma16(qf1, kf1, sacc);
      sc[kt][nt] = sacc;
    }
    __syncthreads();
  }

  // ---- exact row max: regs -> shuffle over ml -> LDS combine over nh ----
  f32x4 rmx = sc[0][0];
#pragma unroll
  for (int kt = 0; kt < 4; ++kt)
#pragma unroll
    for (int nt = 0; nt < 4; ++nt)
#pragma unroll
      for (int r = 0; r < 4; ++r)
        rmx[r] = fmaxf(rmx[r], sc[kt][nt][r]);
#pragma unroll
  for (int off = 1; off <= 8; off <<= 1)
#pragma unroll
    for (int r = 0; r < 4; ++r)
      rmx[r] = fmaxf(rmx[r], __shfl_xor(rmx[r], off));
  if (ml == 0) {
#pragma unroll
    for (int r = 0; r < 4; ++r)
      rcomb[nh][mt][quad * 4 + r] = rmx[r];
  }
  __syncthreads();
  float rm[4];
#pragma unroll
  for (int r = 0; r < 4; ++r)
    rm[r] = 0.125f * fmaxf(rcomb[0][mt][quad * 4 + r], rcomb[1][mt][quad * 4 + r]);

  // ---- phase 2: exp -> Pt, V^T stage, PV MFMA; sums in registers ----
  f32x4 oacc[2] = {};
  float psum[4] = {0.f, 0.f, 0.f, 0.f};
#pragma unroll
  for (int kt = 0; kt < 4; ++kt) {
#pragma unroll
    for (int nt = 0; nt < 4; ++nt) {
#pragma unroll
      for (int r = 0; r < 4; ++r) {
        float p = __expf(sc[kt][nt][r] * 0.125f - rm[r]);   // arg <= 0 exactly
        short pb = f2b(p);
        psum[r] += b2f(pb);   // denominator consistent with bf16 numerator
        Pt[(mt * 16 + quad * 4 + r) * 136 + nh * 64 + nt * 16 + ml] = pb;
      }
    }
#pragma unroll
    for (int i = 0; i < 8; ++i) {          // stage V^T tile [d][key], stride 136
      int u = i * 256 + tid;
      int kp = u >> 5;
      int dp = u & 31;
      const short* vp = qkv + basebs + (size_t)(kt * 128 + kp * 2) * 1536 + 1024 + hoff + dp * 2;
      unsigned int u0 = *(const unsigned int*)vp;
      unsigned int u1 = *(const unsigned int*)(vp + 1536);
      unsigned int w0 = (u0 & 0xffffu) | (u1 << 16);
      unsigned int w1 = (u0 >> 16) | (u1 & 0xffff0000u);
      *(unsigned int*)(VT + (dp * 2) * 136 + kp * 2) = w0;
      *(unsigned int*)(VT + (dp * 2 + 1) * 136 + kp * 2) = w1;
    }
    __syncthreads();   // Pt + VT visible
#pragma unroll
    for (int ks = 0; ks < 4; ++ks) {
      s16x8 pf = *(const s16x8*)(Pt + (mt * 16 + ml) * 136 + ks * 32 + quad * 8);
#pragma unroll
      for (int n2 = 0; n2 < 2; ++n2) {
        const int nd = (nh * 2 + n2) * 16 + ml;
        s16x8 vf = *(const s16x8*)(VT + nd * 136 + ks * 32 + quad * 8);
        oacc[n2] = mfma16(pf, vf, oacc[n2]);
      }
    }
    __syncthreads();   // PV reads done before next-kt Pt/VT rewrite
  }

  // ---- row sums: shuffle over ml, combine over nh via LDS ----
#pragma unroll
  for (int off = 1; off <= 8; off <<= 1)
#pragma unroll
    for (int r = 0; r < 4; ++r)
      psum[r] += __shfl_xor(psum[r], off);
  if (ml == 0) {
#pragma unroll
    for (int r = 0; r < 4; ++r)
      rcomb[nh][mt][quad * 4 + r] = psum[r];
  }
  __syncthreads();

#pragma unroll
  for (int r = 0; r < 4; ++r) {
    const int srow = mt * 16 + quad * 4 + r;
    const float l = rcomb[0][mt][quad * 4 + r] + rcomb[1][mt][quad * 4 + r];
    const float rl = 1.0f / l;
    const int grow = qt * 32 + srow;
#pragma unroll
    for (int n2 = 0; n2 < 2; ++n2) {
      const int d = (nh * 2 + n2) * 16 + ml;
      ctx[((size_t)b * 512 + grow) * 512 + hoff + d] = f2b(oacc[n2][r] * rl);
    }
  }
}

// ---------------- residual + layernorm (in-place on x, fp32 params) -------
__global__ void __launch_bounds__(256)
ln_kernel(short* __restrict__ x, const short* __restrict__ o,
          const float* __restrict__ g, const float* __restrict__ bta) {
  const int row = blockIdx.x * 4 + (threadIdx.x >> 6);
  const int lane = threadIdx.x & 63;
  short* xp = x + (size_t)row * 512 + lane * 8;
  const short* op = o + (size_t)row * 512 + lane * 8;
  s16x8 xv = *(const s16x8*)xp;
  s16x8 ov = *(const s16x8*)op;
  float v[8]; float s = 0.f, s2 = 0.f;
#pragma unroll
  for (int e = 0; e < 8; ++e) {
    float f = b2f(xv[e]) + b2f(ov[e]);
    v[e] = f; s += f; s2 += f * f;
  }
#pragma unroll
  for (int off = 32; off >= 1; off >>= 1) {
    s += __shfl_xor(s, off);
    s2 += __shfl_xor(s2, off);
  }
  const float mean = s * (1.f / 512.f);
  const float var = s2 * (1.f / 512.f) - mean * mean;
  const float rstd = rsqrtf(var + 1e-5f);
  float4 g0 = *(const float4*)(g + lane * 8);
  float4 g1 = *(const float4*)(g + lane * 8 + 4);
  float4 b0 = *(const float4*)(bta + lane * 8);
  float4 b1 = *(const float4*)(bta + lane * 8 + 4);
  float gv[8] = {g0.x, g0.y, g0.z, g0.w, g1.x, g1.y, g1.z, g1.w};
  float bv[8] = {b0.x, b0.y, b0.z, b0.w, b1.x, b1.y, b1.z, b1.w};
  s16x8 outv;
#pragma unroll
  for (int e = 0; e < 8; ++e)
    outv[e] = f2b((v[e] - mean) * rstd * gv[e] + bv[e]);
  *(s16x8*)xp = outv;
}

// ---------------- head ----------------------------------------------------
__global__ void __launch_bounds__(256)
head1_kernel(const short* __restrict__ x, const float* __restrict__ w1,
             const float* __restrict__ b1, const float* __restrict__ w2) {
  const int bidx = blockIdx.x;
  const int b = bidx >> 3, seg = bidx & 7;
  const int tid = threadIdx.x;
  __shared__ float xl[512];
  __shared__ float red[256];
  for (int n = tid; n < 512; n += 256)
    xl[n] = b2f(x[((size_t)b * 512 + 511) * 512 + n]);
  __syncthreads();
  const int f = seg * 256 + tid;
  const float* wr = w1 + (size_t)f * 512;
  float hv = 0.f;
  for (int k8 = 0; k8 < 64; ++k8) {
    float4 wa = *(const float4*)(wr + k8 * 8);
    float4 wb = *(const float4*)(wr + k8 * 8 + 4);
    hv += xl[k8 * 8 + 0] * wa.x + xl[k8 * 8 + 1] * wa.y +
          xl[k8 * 8 + 2] * wa.z + xl[k8 * 8 + 3] * wa.w +
          xl[k8 * 8 + 4] * wb.x + xl[k8 * 8 + 5] * wb.y +
          xl[k8 * 8 + 6] * wb.z + xl[k8 * 8 + 7] * wb.w;
  }
  hv += b1[f];
  hv = fmaxf(hv, 0.f);
  red[tid] = hv * w2[f];
  __syncthreads();
  for (int stride = 128; stride > 0; stride >>= 1) {
    if (tid < stride) red[tid] += red[tid + stride];
    __syncthreads();
  }
  if (tid == 0) g_hpart[bidx] = red[0];
}

__global__ void __launch_bounds__(64)
head2_kernel(const float* __restrict__ b2, float* __restrict__ out) {
  const int t = threadIdx.x;
  if (t < 32) {
    float s = 0.f;
#pragma unroll
    for (int c = 0; c < 8; ++c) s += g_hpart[t * 8 + c];
    out[t] = s + b2[0];
  }
}

extern "C" void kernel_launch(void* const* d_in, const int* in_sizes, int n_in,
                              void* d_out, int out_size, void* d_ws, size_t ws_size,
                              hipStream_t stream) {
  (void)in_sizes; (void)n_in; (void)out_size; (void)ws_size;
  const float* src       = (const float*)d_in[0];
  const float* inp_w     = (const float*)d_in[1];
  const float* inp_b     = (const float*)d_in[2];
  const float* in_proj_w = (const float*)d_in[3];
  const float* in_proj_b = (const float*)d_in[4];
  const float* out_w     = (const float*)d_in[5];
  const float* out_b     = (const float*)d_in[6];
  const float* ff_w1     = (const float*)d_in[7];
  const float* ff_b1     = (const float*)d_in[8];
  const float* ff_w2     = (const float*)d_in[9];
  const float* ff_b2     = (const float*)d_in[10];
  const float* ln1_g     = (const float*)d_in[11];
  const float* ln1_b     = (const float*)d_in[12];
  const float* ln2_g     = (const float*)d_in[13];
  const float* ln2_b     = (const float*)d_in[14];
  const float* op_w1     = (const float*)d_in[15];
  const float* op_b1     = (const float*)d_in[16];
  const float* op_w2     = (const float*)d_in[17];
  const float* op_b2     = (const float*)d_in[18];

  short* ws   = (short*)d_ws;
  short* x    = ws;                              //  8,388,608
  short* qkv  = ws + 8388608;                    // 25,165,824
  short* ctx  = qkv + 25165824;                  //  8,388,608
  short* obuf = ctx + 8388608;                   //  8,388,608
  short* h    = qkv;                             // ff hidden spans qkv+ctx

  cvt2_kernel<<<528, 256, 0, stream>>>(src, inp_w);
  pe_kernel<<<512, 256, 0, stream>>>();
  gemm_bt<2><<<dim3(4, 128), 256, 0, stream>>>(nullptr, 0, inp_b, x, 16384, 512, 64);

  for (int l = 0; l < 6; ++l) {
    cvt4_kernel<<<1536, 256, 0, stream>>>(
        in_proj_w + (size_t)l * 786432, out_w + (size_t)l * 262144,
        ff_w1 + (size_t)l * 1048576, ff_w2 + (size_t)l * 1048576);
    gemm_bt<0><<<dim3(12, 128), 256, 0, stream>>>(
        x, 0, in_proj_b + l * 1536, qkv, 16384, 1536, 512);
    attn_kernel<<<4096, 256, 0, stream>>>(qkv, ctx);
    gemm_bt<0><<<dim3(4, 128), 256, 0, stream>>>(
        ctx, 786432, out_b + l * 512, obuf, 16384, 512, 512);
    ln_kernel<<<4096, 256, 0, stream>>>(x, obuf, ln1_g + l * 512, ln1_b + l * 512);
    gemm_bt<1><<<dim3(16, 128), 256, 0, stream>>>(
        x, 1048576, ff_b1 + l * 2048, h, 16384, 2048, 512);
    gemm_bt<0><<<dim3(4, 128), 256, 0, stream>>>(
        h, 2097152, ff_b2 + l * 512, obuf, 16384, 512, 2048);
    ln_kernel<<<4096, 256, 0, stream>>>(x, obuf, ln2_g + l * 512, ln2_b + l * 512);
  }
  head1_kernel<<<256, 256, 0, stream>>>(x, op_w1, op_b1, op_w2);
  head2_kernel<<<1, 64, 0, stream>>>(op_b2, (float*)d_out);
}

// Round 7
// 1688.465 us; speedup vs baseline: 1.4805x; 1.0610x over previous
//
#include <hip/hip_runtime.h>

typedef short s16x8 __attribute__((ext_vector_type(8)));
typedef float f32x4 __attribute__((ext_vector_type(4)));

// device-global scratch (outside d_ws; fully rewritten every launch)
__device__ short g_wbuf[3145728];   // per-layer bf16 weights: inproj|outw|ffw1|ffw2
__device__ short g_srcb[1048576];   // src as bf16 (16384 x 64)
__device__ short g_inpwb[32768];    // inp_w as bf16 (512 x 64)
__device__ float g_pe[262144];      // positional encoding (512 x 512)
__device__ float g_hpart[256];      // head partials

__device__ inline float b2f(short s) {
  union { unsigned int u; float f; } v;
  v.u = ((unsigned int)(unsigned short)s) << 16;
  return v.f;
}
__device__ inline short f2b(float f) {
  union { float f; unsigned int u; } v; v.f = f;
  unsigned int r = (v.u + 0x7fffu + ((v.u >> 16) & 1u)) >> 16;
  return (short)r;
}
__device__ inline s16x8 pack8(float4 a, float4 b) {
  s16x8 r;
  r[0] = f2b(a.x); r[1] = f2b(a.y); r[2] = f2b(a.z); r[3] = f2b(a.w);
  r[4] = f2b(b.x); r[5] = f2b(b.y); r[6] = f2b(b.z); r[7] = f2b(b.w);
  return r;
}

__device__ inline f32x4 mfma16(s16x8 a, s16x8 b, f32x4 c) {
  return __builtin_amdgcn_mfma_f32_16x16x32_bf16(a, b, c, 0, 0, 0);
}

typedef const __attribute__((address_space(1))) void* as1cptr;
typedef __attribute__((address_space(3))) void* as3ptr;
__device__ inline void gl2lds16(const short* g, short* l) {
  __builtin_amdgcn_global_load_lds((as1cptr)g, (as3ptr)l, 16, 0, 0);
}

// ---------------- fp32 -> bf16 conversion kernels --------------------------
__global__ void __launch_bounds__(256)
cvt2_kernel(const float* __restrict__ i0, const float* __restrict__ i1) {
  const int b = blockIdx.x;
  const float* src; short* dst; int base;
  if (b < 512) { src = i0; dst = g_srcb; base = b; }
  else         { src = i1; dst = g_inpwb; base = b - 512; }
  const int idx = (base * 256 + threadIdx.x) * 8;
  float4 a = *(const float4*)(src + idx);
  float4 c = *(const float4*)(src + idx + 4);
  *(s16x8*)(dst + idx) = pack8(a, c);
}

__global__ void __launch_bounds__(256)
cvt4_kernel(const float* __restrict__ i0, const float* __restrict__ i1,
            const float* __restrict__ i2, const float* __restrict__ i3) {
  const int b = blockIdx.x;
  const float* src; short* dst; int base;
  if (b < 384)       { src = i0; dst = g_wbuf;           base = b; }
  else if (b < 512)  { src = i1; dst = g_wbuf +  786432; base = b - 384; }
  else if (b < 1024) { src = i2; dst = g_wbuf + 1048576; base = b - 512; }
  else               { src = i3; dst = g_wbuf + 2097152; base = b - 1024; }
  const int idx = (base * 256 + threadIdx.x) * 8;
  float4 a = *(const float4*)(src + idx);
  float4 c = *(const float4*)(src + idx + 4);
  *(s16x8*)(dst + idx) = pack8(a, c);
}

// ---------------- PE table: g_pe[s][n] ------------------------------------
__global__ void __launch_bounds__(256)
pe_kernel() {
  const int s = blockIdx.x;
  const int n0 = threadIdx.x * 2;
  const float ang = (float)s * expf((float)n0 * -0.0179889460390160f);
  g_pe[s * 512 + n0]     = sinf(ang);
  g_pe[s * 512 + n0 + 1] = cosf(ang);
}

// ---------------- GEMM: C[M,N] = A[M,K] @ W[N,K]^T + epilogue -------------
// BK=64 (half the barriers of BK=32), XOR-swizzled gl2lds staging:
// lane u stages global chunk ((u&7)^(row&7)) at LDS position (u&7) so that
// fragment reads chunk ((4kk+quad)^(ml&7)) are <=2-way bank aliased (free).
// EPI: 0 = +bias; 1 = relu(+bias); 2 = embed ((acc+bias)*sqrt512 + PE)
template <int EPI>
__global__ void __launch_bounds__(256, 3)
gemm_bt(const short* __restrict__ Ain, int woff, const float* __restrict__ bias,
        short* __restrict__ C, int M, int N, int K) {
  __shared__ short As[128 * 64];   // 16 KB
  __shared__ short Bs[128 * 64];   // 16 KB
  const int tid  = threadIdx.x;
  const int lane = tid & 63;
  const int wave = tid >> 6;
  const int wr = (wave >> 1) << 6;
  const int wc = (wave & 1) << 6;
  const int ml = lane & 15;
  const int quad = lane >> 4;
  const int bm = blockIdx.y, bn = blockIdx.x;

  const short* A = (EPI == 2) ? (const short*)g_srcb : Ain;
  const short* W = (EPI == 2) ? (const short*)g_inpwb : (const short*)(g_wbuf + woff);

  // staging decode (4 calls x 256 threads cover 128 rows x 8 chunks)
  int srow[4], soff[4];
#pragma unroll
  for (int i = 0; i < 4; ++i) {
    const int u = i * 256 + tid;
    srow[i] = u >> 3;
    soff[i] = ((u & 7) ^ ((u >> 3) & 7)) << 3;   // swizzled global chunk byte/2
  }
  const int rsw = (ml & 7);                       // read-side swizzle key
  f32x4 acc[4][4] = {};

  for (int k0 = 0; k0 < K; k0 += 64) {
#pragma unroll
    for (int i = 0; i < 4; ++i) {
      gl2lds16(A + (size_t)(bm * 128 + srow[i]) * K + k0 + soff[i],
               As + (i * 256 + tid) * 8);
      gl2lds16(W + (size_t)(bn * 128 + srow[i]) * K + k0 + soff[i],
               Bs + (i * 256 + tid) * 8);
    }
    __syncthreads();
#pragma unroll
    for (int kk = 0; kk < 2; ++kk) {
      const int rchunk = ((kk * 4 + quad) ^ rsw) * 8;
      s16x8 af[4], bfr[4];
#pragma unroll
      for (int i = 0; i < 4; ++i)
        af[i] = *(const s16x8*)(As + (wr + i * 16 + ml) * 64 + rchunk);
#pragma unroll
      for (int j = 0; j < 4; ++j)
        bfr[j] = *(const s16x8*)(Bs + (wc + j * 16 + ml) * 64 + rchunk);
#pragma unroll
      for (int i = 0; i < 4; ++i)
#pragma unroll
        for (int j = 0; j < 4; ++j)
          acc[i][j] = mfma16(af[i], bfr[j], acc[i][j]);
    }
    __syncthreads();
  }

#pragma unroll
  for (int j = 0; j < 4; ++j) {
    const int col = bn * 128 + wc + j * 16 + ml;
    const float bv = bias[col];
#pragma unroll
    for (int i = 0; i < 4; ++i) {
      const int row0 = bm * 128 + wr + i * 16 + quad * 4;
#pragma unroll
      for (int r = 0; r < 4; ++r) {
        float v = acc[i][j][r] + bv;
        if (EPI == 1) v = fmaxf(v, 0.0f);
        if (EPI == 2) {
          const int s = (row0 + r) & 511;
          v = (acc[i][j][r] + bv) * 22.62741699796952f + g_pe[s * 512 + col];
        }
        C[(size_t)(row0 + r) * N + col] = f2b(v);
      }
    }
  }
}

// ---------------- fused attention, single pass (unchanged from R6) --------
__global__ void __launch_bounds__(256, 3)
attn_kernel(const short* __restrict__ qkv, short* __restrict__ ctx) {
  __shared__ short KT[128 * 72];     // 18432 B
  __shared__ short VT[64 * 136];     // 17408 B
  __shared__ short Pt[32 * 136];     // 8704 B
  __shared__ float rcomb[2][2][16];  // [nh][mt][row16]: max, then sums
  const int tid = threadIdx.x;
  const int lane = tid & 63, wave = tid >> 6;
  const int ml = lane & 15, quad = lane >> 4;
  const int mt = wave & 1, nh = wave >> 1;
  const int bx = blockIdx.x;
  const int qt = bx >> 8;
  const int bh = bx & 255;
  const int b = bh >> 3, h = bh & 7;
  const size_t basebs = (size_t)b * 512 * 1536;
  const int hoff = h * 64;

  s16x8 qf0, qf1;
  {
    const int qrow = qt * 32 + mt * 16 + ml;
    const short* qp = qkv + basebs + (size_t)qrow * 1536 + hoff;
    qf0 = *(const s16x8*)(qp + quad * 8);
    qf1 = *(const s16x8*)(qp + 32 + quad * 8);
  }

  // ---- phase 1: all scores into registers ----
  f32x4 sc[4][4];
#pragma unroll
  for (int kt = 0; kt < 4; ++kt) {
#pragma unroll
    for (int i = 0; i < 4; ++i) {          // stage K tile: 128 keys x 64 d
      int u = i * 256 + tid;
      int key = u >> 3;
      int d8 = (u & 7) << 3;
      const short* kp = qkv + basebs + (size_t)(kt * 128 + key) * 1536 + 512 + hoff + d8;
      *(s16x8*)(KT + key * 72 + d8) = *(const s16x8*)kp;
    }
    __syncthreads();
#pragma unroll
    for (int nt = 0; nt < 4; ++nt) {
      const int nrow = nh * 64 + nt * 16 + ml;
      f32x4 sacc = {};
      s16x8 kf0 = *(const s16x8*)(KT + nrow * 72 + quad * 8);
      s16x8 kf1 = *(const s16x8*)(KT + nrow * 72 + 32 + quad * 8);
      sacc = mfma16(qf0, kf0, sacc);
      sacc = mfma16(qf1, kf1, sacc);
      sc[kt][nt] = sacc;
    }
    __syncthreads();
  }

  // ---- exact row max ----
  f32x4 rmx = sc[0][0];
#pragma unroll
  for (int kt = 0; kt < 4; ++kt)
#pragma unroll
    for (int nt = 0; nt < 4; ++nt)
#pragma unroll
      for (int r = 0; r < 4; ++r)
        rmx[r] = fmaxf(rmx[r], sc[kt][nt][r]);
#pragma unroll
  for (int off = 1; off <= 8; off <<= 1)
#pragma unroll
    for (int r = 0; r < 4; ++r)
      rmx[r] = fmaxf(rmx[r], __shfl_xor(rmx[r], off));
  if (ml == 0) {
#pragma unroll
    for (int r = 0; r < 4; ++r)
      rcomb[nh][mt][quad * 4 + r] = rmx[r];
  }
  __syncthreads();
  float rm[4];
#pragma unroll
  for (int r = 0; r < 4; ++r)
    rm[r] = 0.125f * fmaxf(rcomb[0][mt][quad * 4 + r], rcomb[1][mt][quad * 4 + r]);

  // ---- phase 2: exp -> Pt, V^T stage, PV MFMA ----
  f32x4 oacc[2] = {};
  float psum[4] = {0.f, 0.f, 0.f, 0.f};
#pragma unroll
  for (int kt = 0; kt < 4; ++kt) {
#pragma unroll
    for (int nt = 0; nt < 4; ++nt) {
#pragma unroll
      for (int r = 0; r < 4; ++r) {
        float p = __expf(sc[kt][nt][r] * 0.125f - rm[r]);   // arg <= 0 exactly
        short pb = f2b(p);
        psum[r] += b2f(pb);
        Pt[(mt * 16 + quad * 4 + r) * 136 + nh * 64 + nt * 16 + ml] = pb;
      }
    }
#pragma unroll
    for (int i = 0; i < 8; ++i) {          // stage V^T tile [d][key], stride 136
      int u = i * 256 + tid;
      int kp = u >> 5;
      int dp = u & 31;
      const short* vp = qkv + basebs + (size_t)(kt * 128 + kp * 2) * 1536 + 1024 + hoff + dp * 2;
      unsigned int u0 = *(const unsigned int*)vp;
      unsigned int u1 = *(const unsigned int*)(vp + 1536);
      unsigned int w0 = (u0 & 0xffffu) | (u1 << 16);
      unsigned int w1 = (u0 >> 16) | (u1 & 0xffff0000u);
      *(unsigned int*)(VT + (dp * 2) * 136 + kp * 2) = w0;
      *(unsigned int*)(VT + (dp * 2 + 1) * 136 + kp * 2) = w1;
    }
    __syncthreads();   // Pt + VT visible
#pragma unroll
    for (int ks = 0; ks < 4; ++ks) {
      s16x8 pf = *(const s16x8*)(Pt + (mt * 16 + ml) * 136 + ks * 32 + quad * 8);
#pragma unroll
      for (int n2 = 0; n2 < 2; ++n2) {
        const int nd = (nh * 2 + n2) * 16 + ml;
        s16x8 vf = *(const s16x8*)(VT + nd * 136 + ks * 32 + quad * 8);
        oacc[n2] = mfma16(pf, vf, oacc[n2]);
      }
    }
    __syncthreads();   // PV reads done before next-kt Pt/VT rewrite
  }

  // ---- row sums ----
#pragma unroll
  for (int off = 1; off <= 8; off <<= 1)
#pragma unroll
    for (int r = 0; r < 4; ++r)
      psum[r] += __shfl_xor(psum[r], off);
  if (ml == 0) {
#pragma unroll
    for (int r = 0; r < 4; ++r)
      rcomb[nh][mt][quad * 4 + r] = psum[r];
  }
  __syncthreads();

#pragma unroll
  for (int r = 0; r < 4; ++r) {
    const int srow = mt * 16 + quad * 4 + r;
    const float l = rcomb[0][mt][quad * 4 + r] + rcomb[1][mt][quad * 4 + r];
    const float rl = 1.0f / l;
    const int grow = qt * 32 + srow;
#pragma unroll
    for (int n2 = 0; n2 < 2; ++n2) {
      const int d = (nh * 2 + n2) * 16 + ml;
      ctx[((size_t)b * 512 + grow) * 512 + hoff + d] = f2b(oacc[n2][r] * rl);
    }
  }
}

// ---------------- residual + layernorm (in-place on x, fp32 params) -------
__global__ void __launch_bounds__(256)
ln_kernel(short* __restrict__ x, const short* __restrict__ o,
          const float* __restrict__ g, const float* __restrict__ bta) {
  const int row = blockIdx.x * 4 + (threadIdx.x >> 6);
  const int lane = threadIdx.x & 63;
  short* xp = x + (size_t)row * 512 + lane * 8;
  const short* op = o + (size_t)row * 512 + lane * 8;
  s16x8 xv = *(const s16x8*)xp;
  s16x8 ov = *(const s16x8*)op;
  float v[8]; float s = 0.f, s2 = 0.f;
#pragma unroll
  for (int e = 0; e < 8; ++e) {
    float f = b2f(xv[e]) + b2f(ov[e]);
    v[e] = f; s += f; s2 += f * f;
  }
#pragma unroll
  for (int off = 32; off >= 1; off >>= 1) {
    s += __shfl_xor(s, off);
    s2 += __shfl_xor(s2, off);
  }
  const float mean = s * (1.f / 512.f);
  const float var = s2 * (1.f / 512.f) - mean * mean;
  const float rstd = rsqrtf(var + 1e-5f);
  float4 g0 = *(const float4*)(g + lane * 8);
  float4 g1 = *(const float4*)(g + lane * 8 + 4);
  float4 b0 = *(const float4*)(bta + lane * 8);
  float4 b1 = *(const float4*)(bta + lane * 8 + 4);
  float gv[8] = {g0.x, g0.y, g0.z, g0.w, g1.x, g1.y, g1.z, g1.w};
  float bv[8] = {b0.x, b0.y, b0.z, b0.w, b1.x, b1.y, b1.z, b1.w};
  s16x8 outv;
#pragma unroll
  for (int e = 0; e < 8; ++e)
    outv[e] = f2b((v[e] - mean) * rstd * gv[e] + bv[e]);
  *(s16x8*)xp = outv;
}

// ---------------- head ----------------------------------------------------
__global__ void __launch_bounds__(256)
head1_kernel(const short* __restrict__ x, const float* __restrict__ w1,
             const float* __restrict__ b1, const float* __restrict__ w2) {
  const int bidx = blockIdx.x;
  const int b = bidx >> 3, seg = bidx & 7;
  const int tid = threadIdx.x;
  __shared__ float xl[512];
  __shared__ float red[256];
  for (int n = tid; n < 512; n += 256)
    xl[n] = b2f(x[((size_t)b * 512 + 511) * 512 + n]);
  __syncthreads();
  const int f = seg * 256 + tid;
  const float* wr = w1 + (size_t)f * 512;
  float hv = 0.f;
  for (int k8 = 0; k8 < 64; ++k8) {
    float4 wa = *(const float4*)(wr + k8 * 8);
    float4 wb = *(const float4*)(wr + k8 * 8 + 4);
    hv += xl[k8 * 8 + 0] * wa.x + xl[k8 * 8 + 1] * wa.y +
          xl[k8 * 8 + 2] * wa.z + xl[k8 * 8 + 3] * wa.w +
          xl[k8 * 8 + 4] * wb.x + xl[k8 * 8 + 5] * wb.y +
          xl[k8 * 8 + 6] * wb.z + xl[k8 * 8 + 7] * wb.w;
  }
  hv += b1[f];
  hv = fmaxf(hv, 0.f);
  red[tid] = hv * w2[f];
  __syncthreads();
  for (int stride = 128; stride > 0; stride >>= 1) {
    if (tid < stride) red[tid] += red[tid + stride];
    __syncthreads();
  }
  if (tid == 0) g_hpart[bidx] = red[0];
}

__global__ void __launch_bounds__(64)
head2_kernel(const float* __restrict__ b2, float* __restrict__ out) {
  const int t = threadIdx.x;
  if (t < 32) {
    float s = 0.f;
#pragma unroll
    for (int c = 0; c < 8; ++c) s += g_hpart[t * 8 + c];
    out[t] = s + b2[0];
  }
}

extern "C" void kernel_launch(void* const* d_in, const int* in_sizes, int n_in,
                              void* d_out, int out_size, void* d_ws, size_t ws_size,
                              hipStream_t stream) {
  (void)in_sizes; (void)n_in; (void)out_size; (void)ws_size;
  const float* src       = (const float*)d_in[0];
  const float* inp_w     = (const float*)d_in[1];
  const float* inp_b     = (const float*)d_in[2];
  const float* in_proj_w = (const float*)d_in[3];
  const float* in_proj_b = (const float*)d_in[4];
  const float* out_w     = (const float*)d_in[5];
  const float* out_b     = (const float*)d_in[6];
  const float* ff_w1     = (const float*)d_in[7];
  const float* ff_b1     = (const float*)d_in[8];
  const float* ff_w2     = (const float*)d_in[9];
  const float* ff_b2     = (const float*)d_in[10];
  const float* ln1_g     = (const float*)d_in[11];
  const float* ln1_b     = (const float*)d_in[12];
  const float* ln2_g     = (const float*)d_in[13];
  const float* ln2_b     = (const float*)d_in[14];
  const float* op_w1     = (const float*)d_in[15];
  const float* op_b1     = (const float*)d_in[16];
  const float* op_w2     = (const float*)d_in[17];
  const float* op_b2     = (const float*)d_in[18];

  short* ws   = (short*)d_ws;
  short* x    = ws;                              //  8,388,608
  short* qkv  = ws + 8388608;                    // 25,165,824
  short* ctx  = qkv + 25165824;                  //  8,388,608
  short* obuf = ctx + 8388608;                   //  8,388,608
  short* h    = qkv;                             // ff hidden spans qkv+ctx

  cvt2_kernel<<<528, 256, 0, stream>>>(src, inp_w);
  pe_kernel<<<512, 256, 0, stream>>>();
  gemm_bt<2><<<dim3(4, 128), 256, 0, stream>>>(nullptr, 0, inp_b, x, 16384, 512, 64);

  for (int l = 0; l < 6; ++l) {
    cvt4_kernel<<<1536, 256, 0, stream>>>(
        in_proj_w + (size_t)l * 786432, out_w + (size_t)l * 262144,
        ff_w1 + (size_t)l * 1048576, ff_w2 + (size_t)l * 1048576);
    gemm_bt<0><<<dim3(12, 128), 256, 0, stream>>>(
        x, 0, in_proj_b + l * 1536, qkv, 16384, 1536, 512);
    attn_kernel<<<4096, 256, 0, stream>>>(qkv, ctx);
    gemm_bt<0><<<dim3(4, 128), 256, 0, stream>>>(
        ctx, 786432, out_b + l * 512, obuf, 16384, 512, 512);
    ln_kernel<<<4096, 256, 0, stream>>>(x, obuf, ln1_g + l * 512, ln1_b + l * 512);
    gemm_bt<1><<<dim3(16, 128), 256, 0, stream>>>(
        x, 1048576, ff_b1 + l * 2048, h, 16384, 2048, 512);
    gemm_bt<0><<<dim3(4, 128), 256, 0, stream>>>(
        h, 2097152, ff_b2 + l * 512, obuf, 16384, 512, 2048);
    ln_kernel<<<4096, 256, 0, stream>>>(x, obuf, ln2_g + l * 512, ln2_b + l * 512);
  }
  head1_kernel<<<256, 256, 0, stream>>>(x, op_w1, op_b1, op_w2);
  head2_kernel<<<1, 64, 0, stream>>>(op_b2, (float*)d_out);
}